// Round 4
// baseline (359.655 us; speedup 1.0000x reference)
//
#include <hip/hip_runtime.h>
#include <hip/hip_fp16.h>

// out[b,o] = sum_{i,n} x[b,i]*noise[b,n]*hW[i*512+o,n]      (main, branch 0, z=0..15)
//          + sum_{i,n} px[b,i]*noise[b,n]*pW[i*512+o,n]     (main, branch 1, z=16..31)
//          + sum_i x[b,i]*hb[i*512+o] (+ prior)             (E1: extra K=32 MFMA after loop)
//          + sum_n noise[b,n]*(hW[MAIN_D+o,n]+pW[...,n])    (E2: macro 33 on z%16==0)
//          + hb[MAIN_D+o] + pb[MAIN_D+o]                    (folded into reduce kernel)
//
// R7: R6 geometry (256 blocks x 256b x 128o, 1 block/CU, plain-store split-K) +
//     depth-2 W prefetch (two named reg sets, loads span 2 macros / 2 barriers,
//     counted vmcnt) + raw s_barrier with lgkmcnt(0)-only (no vmcnt drain per
//     macro -> HBM demand smoothed instead of per-barrier bursts) + setprio
//     around MFMA clusters. Race ledger: dbuf write->barrier->read structure
//     unchanged; in-flight globals are register-destined (no cross-wave vis).

#define MAIN_D (512*512)

typedef _Float16 half8 __attribute__((ext_vector_type(8)));
typedef float floatx4 __attribute__((ext_vector_type(4)));

static __device__ __forceinline__ unsigned pk2(float a, float b) {
    union { __half2 h; unsigned u; } c;
    c.h = __float22half2_rn(make_float2(a, b));
    return c.u;
}

// ---- reduce: out[b,o] = hb[MAIN_D+o] + pb[MAIN_D+o] + sum_z ws[z][b][o] ----
__global__ __launch_bounds__(256) void reduce_kernel(
    const float* __restrict__ ws,
    const float* __restrict__ hb, const float* __restrict__ pb,
    float* __restrict__ out)
{
    const int idx = blockIdx.x * 256 + threadIdx.x;   // 65536 threads x float4
    const int o4 = (idx * 4) & 511;
    float4 acc;
    acc.x = hb[MAIN_D + o4 + 0] + pb[MAIN_D + o4 + 0];
    acc.y = hb[MAIN_D + o4 + 1] + pb[MAIN_D + o4 + 1];
    acc.z = hb[MAIN_D + o4 + 2] + pb[MAIN_D + o4 + 2];
    acc.w = hb[MAIN_D + o4 + 3] + pb[MAIN_D + o4 + 3];
#pragma unroll
    for (int zz = 0; zz < 32; ++zz) {
        float4 v = *(const float4*)(ws + (long)zz * (512 * 512) + idx * 4);
        acc.x += v.x; acc.y += v.y; acc.z += v.z; acc.w += v.w;
    }
    *(float4*)(out + idx * 4) = acc;
}

// one macro step: write slab M from WA/WB regs into Bl[BUFI], issue loads for
// slab M+2 back into WA/WB (consumed 2 barriers later -> counted vmcnt),
// raw barrier (lgkmcnt-only), then 4 q-phases of reads + MFMA.
#define MACRO_BODY(WA, WB, BUFI)                                              \
  do {                                                                        \
    _Float16* buf = &Bl[BUFI][0];                                             \
    _Pragma("unroll")                                                         \
    for (int j = 0; j < 4; ++j) {                                             \
      int c = j * 512 + t;                                                    \
      int row = c >> 4, col8 = (c & 15) * 8;                                  \
      *(uint4*)&buf[row * 136 + col8] = make_uint4(                           \
          pk2(WA[j].x, WA[j].y), pk2(WA[j].z, WA[j].w),                       \
          pk2(WB[j].x, WB[j].y), pk2(WB[j].z, WB[j].w));                      \
    }                                                                         \
    if (m + 2 < nmacro) {                                                     \
      long rb = (m + 2 < 32) ? (long)((ic0 + m + 2) * 512 + o0)               \
                             : (long)(MAIN_D + o0);                           \
      const float* p = Ws + rb * 128;                                         \
      _Pragma("unroll")                                                       \
      for (int j = 0; j < 4; ++j) {                                           \
        int c = j * 512 + t;                                                  \
        int off = (c >> 4) * 128 + (c & 15) * 8;                              \
        WA[j] = *(const float4*)(p + off);                                    \
        WB[j] = *(const float4*)(p + off + 4);                                \
      }                                                                       \
    }                                                                         \
    asm volatile("" ::: "memory");                                            \
    asm volatile("s_waitcnt lgkmcnt(0)" ::: "memory");                        \
    __builtin_amdgcn_s_barrier();                                             \
    __builtin_amdgcn_sched_barrier(0);                                        \
    asm volatile("" ::: "memory");                                            \
    const bool isE2 = (m >= 32);                                              \
    _Float16 xs[4];                                                           \
    if (!isE2) {                                                              \
      _Pragma("unroll")                                                       \
      for (int mf = 0; mf < 4; ++mf)                                          \
        xs[mf] = xhl[(wm64 + mf * 16 + l16) * 40 + m];                        \
    }                                                                         \
    _Pragma("unroll")                                                         \
    for (int q = 0; q < 4; ++q) {                                             \
      half8 bfr[4], afr[4];                                                   \
      _Pragma("unroll")                                                       \
      for (int nf = 0; nf < 4; ++nf)                                          \
        bfr[nf] = *(half8*)&buf[(wn64 + nf * 16 + l16) * 136 + q * 32 + quad * 8]; \
      _Pragma("unroll")                                                       \
      for (int mf = 0; mf < 4; ++mf) {                                        \
        if (isE2) afr[mf] = nzf[mf][q];                                       \
        else {                                                                \
          half8 xv;                                                           \
          _Pragma("unroll")                                                   \
          for (int jj = 0; jj < 8; ++jj) xv[jj] = xs[mf];                     \
          afr[mf] = nzf[mf][q] * xv;                                          \
        }                                                                     \
      }                                                                       \
      __builtin_amdgcn_s_setprio(1);                                          \
      _Pragma("unroll")                                                       \
      for (int mf = 0; mf < 4; ++mf)                                          \
        _Pragma("unroll")                                                     \
        for (int nf = 0; nf < 4; ++nf)                                        \
          acc[mf][nf] = __builtin_amdgcn_mfma_f32_16x16x32_f16(               \
              afr[mf], bfr[nf], acc[mf][nf], 0, 0, 0);                        \
      __builtin_amdgcn_s_setprio(0);                                          \
    }                                                                         \
  } while (0)

// ---- main: 256 blocks x 512 threads (8 waves, 4m x 2n of 64x64 tiles) ----
__global__ __launch_bounds__(512, 2) void main_gemm(
    const float* __restrict__ x, const float* __restrict__ px,
    const float* __restrict__ noise,
    const float* __restrict__ hW, const float* __restrict__ hb,
    const float* __restrict__ pW, const float* __restrict__ pb,
    float* __restrict__ ws)
{
    // W tile double buffer [2][128 o][136 halfs] (cols 0..127 = n). 69632 B.
    // Prologue overlay: noise staging [256 b][136 halfs].
    __shared__ __attribute__((aligned(16))) _Float16 Bl[2][128 * 136];
    __shared__ __attribute__((aligned(16))) _Float16 xhl[256 * 40];  // x [b][i] half

    const int t = threadIdx.x;
    // sibling-swizzled decode: the 2 blocks sharing a W slab are 8 apart in
    // linear index (same XCD under round-robin dispatch) -> L2 slab sharing.
    const int lin  = blockIdx.x;            // 0..255
    const int s    = (lin >> 3) & 1;        // b-tile (sibling id)
    const int g    = ((lin >> 4) << 3) | (lin & 7);   // 0..127 slab group
    const int z    = g >> 2;                // 0..31: branch*16 + i-chunk
    const int y    = g & 3;                 // o-tile
    const int b0   = s * 256;
    const int o0   = y * 128;
    const int branch = z >> 4;
    const int ic0  = (z & 15) * 32;
    const float* __restrict__ xsrc = branch ? px : x;
    const float* __restrict__ Ws   = branch ? pW : hW;
    const float* __restrict__ bias = branch ? pb : hb;
    const int nmacro = ((z & 15) == 0) ? 33 : 32;

    // ---- stage x tile 256b x 32i -> half, stride 40 ----
#pragma unroll
    for (int k = 0; k < 4; ++k) {
        int idx = k * 512 + t;              // 0..2047
        int bb = idx >> 3, c = (idx & 7) * 4;
        float4 v = *(const float4*)(xsrc + (b0 + bb) * 512 + ic0 + c);
        *(unsigned*)&xhl[bb * 40 + c]     = pk2(v.x, v.y);
        *(unsigned*)&xhl[bb * 40 + c + 2] = pk2(v.z, v.w);
    }
    // ---- stage noise 256b x 128n -> half into Bl overlay, stride 136 ----
    _Float16* nzl = &Bl[0][0];
#pragma unroll
    for (int k = 0; k < 16; ++k) {
        int idx = k * 512 + t;              // 0..8191
        int bb = idx >> 5, c = (idx & 31) * 4;
        float4 v = *(const float4*)(noise + (b0 + bb) * 128 + c);
        *(unsigned*)&nzl[bb * 136 + c]     = pk2(v.x, v.y);
        *(unsigned*)&nzl[bb * 136 + c + 2] = pk2(v.z, v.w);
    }
    __syncthreads();

    const int lane = t & 63;
    const int w    = t >> 6;
    const int wm64 = (w >> 1) * 64;         // 0,64,128,192
    const int wn64 = (w & 1) * 64;          // 0,64
    const int quad = lane >> 4;
    const int l16  = lane & 15;

    // noise A-fragments in registers: nzf[mf][q][j] = nz_h[row][q*32+quad*8+j]
    half8 nzf[4][4];
#pragma unroll
    for (int mf = 0; mf < 4; ++mf)
#pragma unroll
        for (int q = 0; q < 4; ++q)
            nzf[mf][q] = *(half8*)&nzl[(wm64 + mf * 16 + l16) * 136 + q * 32 + quad * 8];

    floatx4 acc[4][4];
#pragma unroll
    for (int a = 0; a < 4; ++a)
#pragma unroll
        for (int b = 0; b < 4; ++b) acc[a][b] = (floatx4)0.0f;

    // W slab staging, depth-2: two named reg sets (no runtime indexing ->
    // stays in VGPRs). Slab 0 -> set0, slab 1 -> set1.
    float4 wa0[4], wb0[4], wa1[4], wb1[4];
    {
        const float* p0 = Ws + (long)(ic0 * 512 + o0) * 128;
        const float* p1 = Ws + (long)((ic0 + 1) * 512 + o0) * 128;
#pragma unroll
        for (int j = 0; j < 4; ++j) {
            int c = j * 512 + t;
            int off = (c >> 4) * 128 + (c & 15) * 8;
            wa0[j] = *(const float4*)(p0 + off);
            wb0[j] = *(const float4*)(p0 + off + 4);
            wa1[j] = *(const float4*)(p1 + off);
            wb1[j] = *(const float4*)(p1 + off + 4);
        }
    }
    __syncthreads();   // nzf overlay reads complete before first Bl write

    int m = 0;
    while (true) {
        MACRO_BODY(wa0, wb0, 0);            // even m -> buffer 0
        ++m; if (m >= nmacro) break;
        MACRO_BODY(wa1, wb1, 1);            // odd m -> buffer 1
        ++m; if (m >= nmacro) break;
    }

    // ---- E1: bias GEMM step, K=32 (A = x tile in LDS) ----
    __syncthreads();
    {
        const int oo = t >> 2, kh = (t & 3) * 8;
        float tmp[8];
#pragma unroll
        for (int j = 0; j < 8; ++j)
            tmp[j] = bias[(long)(ic0 + kh + j) * 512 + o0 + oo];
        *(uint4*)&Bl[0][oo * 136 + kh] = make_uint4(
            pk2(tmp[0], tmp[1]), pk2(tmp[2], tmp[3]),
            pk2(tmp[4], tmp[5]), pk2(tmp[6], tmp[7]));
    }
    __syncthreads();
    {
        half8 afr[4], bfr[4];
#pragma unroll
        for (int mf = 0; mf < 4; ++mf)
            afr[mf] = *(half8*)&xhl[(wm64 + mf * 16 + l16) * 40 + quad * 8];
#pragma unroll
        for (int nf = 0; nf < 4; ++nf)
            bfr[nf] = *(half8*)&Bl[0][(wn64 + nf * 16 + l16) * 136 + quad * 8];
#pragma unroll
        for (int mf = 0; mf < 4; ++mf)
#pragma unroll
            for (int nf = 0; nf < 4; ++nf)
                acc[mf][nf] = __builtin_amdgcn_mfma_f32_16x16x32_f16(
                    afr[mf], bfr[nf], acc[mf][nf], 0, 0, 0);
    }

    // ---- split-K partials: plain stores, unique writer per ws element ----
    // (C/D: row=quad*4+r, col=l16; verified R1/R2)
    float* wsl = ws + (long)z * (512 * 512);
#pragma unroll
    for (int mf = 0; mf < 4; ++mf)
#pragma unroll
        for (int nf = 0; nf < 4; ++nf)
#pragma unroll
            for (int r = 0; r < 4; ++r) {
                int row = b0 + wm64 + mf * 16 + quad * 4 + r;
                int col = o0 + wn64 + nf * 16 + l16;
                wsl[row * 512 + col] = acc[mf][nf][r];
            }
}

extern "C" void kernel_launch(void* const* d_in, const int* in_sizes, int n_in,
                              void* d_out, int out_size, void* d_ws, size_t ws_size,
                              hipStream_t stream) {
    const float* x  = (const float*)d_in[0];
    const float* px = (const float*)d_in[1];
    const float* nz = (const float*)d_in[2];
    const float* hW = (const float*)d_in[3];
    const float* hb = (const float*)d_in[4];
    const float* pW = (const float*)d_in[5];
    const float* pb = (const float*)d_in[6];
    float* out = (float*)d_out;
    float* ws  = (float*)d_ws;   // 32 slices x 1MB = 32MB split-K partials

    hipLaunchKernelGGL(main_gemm, dim3(256), dim3(512), 0, stream,
                       x, px, nz, hW, hb, pW, pb, ws);
    hipLaunchKernelGGL(reduce_kernel, dim3(256), dim3(256), 0, stream,
                       ws, hb, pb, out);
}